// Round 3
// baseline (231.270 us; speedup 1.0000x reference)
//
#include <hip/hip_runtime.h>
#include <hip/hip_bf16.h>

// DenSparse: out[b, dst_e] += w_e * x[b, src_e]
// B=32, IN=OUT=65536, NNZ=1048576
//
// Round 3: 256-way partition by dst>>8 with dense (run-contiguous) writes,
// then per-bucket LDS accumulation (ds_add_f32) -> coalesced output slab.
// Round-2 lesson: random 4B-granularity writes (atomic OR plain) cost a full
// 64B line each (WRITE_SIZE was 110MB). All scatter writes here are ~16-edge
// contiguous runs. x_t stored as bf16 (4MB) so it is L2-resident per XCD.

#define IN_SIZE  65536
#define OUT_SIZE 65536
#define BATCH    32
#define NBLK     256      // partition blocks
#define NBKT     256      // buckets (dst >> 8)

typedef unsigned int uint;

// ---------------- x[32][IN] -> xt_bf16[IN][32] ----------------
__global__ void transpose_in_bf16(const float* __restrict__ x,
                                  __hip_bfloat16* __restrict__ xt) {
    __shared__ float tile[32][33];
    int i0 = blockIdx.x * 32;
    int tx = threadIdx.x & 31;
    int ty = threadIdx.x >> 5;
    tile[ty][tx] = x[(size_t)ty * IN_SIZE + i0 + tx];
    __syncthreads();
    xt[((size_t)(i0 + ty)) * BATCH + tx] = __float2bfloat16(tile[tx][ty]);
}

// ---------------- pass A: per-block histogram of dst>>8 ----------------
__global__ void hist_part(const int* __restrict__ dst, int* __restrict__ bhist,
                          int nnz, int epb) {
    __shared__ int h[NBKT];
    int blk = blockIdx.x, tid = threadIdx.x;
    h[tid] = 0;
    __syncthreads();
    int base = blk * epb;
    int lim  = min(nnz, base + epb);
    for (int e = base + tid; e < lim; e += 256)
        atomicAdd(&h[dst[e] >> 8], 1);
    __syncthreads();
    // bucket-major layout: bhist[q*NBLK + blk]
    bhist[(tid << 8) | blk] = h[tid];
}

// ---------------- pass B: exclusive scan of 65536 counters ----------------
// single WG, 1024 threads x 64 elements. goff has 65537 entries.
__global__ void scan_hist(const int* __restrict__ bhist, int* __restrict__ goff) {
    __shared__ int sums[1024];
    const int tid  = threadIdx.x;
    const int base = tid * 64;
    const int4* c4 = (const int4*)(bhist + base);
    int4 v[16];
    int lsum = 0;
    #pragma unroll
    for (int j = 0; j < 16; ++j) {
        v[j] = c4[j];
        lsum += v[j].x + v[j].y + v[j].z + v[j].w;
    }
    sums[tid] = lsum;
    __syncthreads();
    for (int ofs = 1; ofs < 1024; ofs <<= 1) {
        int t = (tid >= ofs) ? sums[tid - ofs] : 0;
        __syncthreads();
        sums[tid] += t;
        __syncthreads();
    }
    int run = sums[tid] - lsum;   // exclusive base of this thread's 64 elems
    #pragma unroll
    for (int j = 0; j < 16; ++j) {
        goff[base + j * 4 + 0] = run; run += v[j].x;
        goff[base + j * 4 + 1] = run; run += v[j].y;
        goff[base + j * 4 + 2] = run; run += v[j].z;
        goff[base + j * 4 + 3] = run; run += v[j].w;
    }
    if (tid == 1023) goff[NBKT * NBLK] = run;   // == nnz
}

// ---------------- pass C: partition edges (dense run writes) ----------------
__global__ void partition_edges(const int* __restrict__ dst,
                                const int* __restrict__ src,
                                const float* __restrict__ w,
                                const int* __restrict__ goff,
                                uint*  __restrict__ meta,
                                float* __restrict__ wf,
                                int nnz, int epb) {
    __shared__ int cur[NBKT];
    int blk = blockIdx.x, tid = threadIdx.x;
    cur[tid] = goff[(tid << 8) | blk];   // start offset of (bucket=tid, blk) run
    __syncthreads();
    int base = blk * epb;
    int lim  = min(nnz, base + epb);
    for (int e = base + tid; e < lim; e += 256) {
        int d = dst[e];
        int q = d >> 8;
        int pos = atomicAdd(&cur[q], 1);   // run positions are block-private
        meta[pos] = (uint)(src[e] & 0xFFFF) | ((uint)(d & 0xFF) << 16);
        wf[pos]   = w[e];
    }
}

// ---------------- pass D: per-bucket LDS accumulate + coalesced out ----------------
__global__ __launch_bounds__(1024) void accum_bucket(
        const __hip_bfloat16* __restrict__ xt,
        const uint*  __restrict__ meta,
        const float* __restrict__ wf,
        const int*   __restrict__ goff,
        float* __restrict__ out) {
    __shared__ float acc[256 * 33];   // [dst_low][batch], 33-pad: conflict-free
    const int q   = blockIdx.x;
    const int tid = threadIdx.x;
    for (int i = tid; i < 256 * 33; i += 1024) acc[i] = 0.f;
    __syncthreads();
    const int beg = goff[q << 8];
    const int end = goff[(q + 1) << 8];   // q=255 -> goff[65536] = nnz
    const int hw = tid >> 5;    // half-wave id: 0..31, one edge per iteration
    const int b  = tid & 31;    // batch lane
    #pragma unroll 2
    for (int i = beg + hw; i < end; i += 32) {
        uint  m  = meta[i];            // broadcast within half-wave
        float wv = wf[i];              // broadcast
        int   s  = m & 0xFFFF;
        int   d8 = (m >> 16) & 0xFF;
        float xv = __bfloat162float(xt[s * BATCH + b]);  // one 64B line/edge
        atomicAdd(&acc[d8 * 33 + b], wv * xv);           // ds_add_f32, no conflicts
    }
    __syncthreads();
    // write out[row][q*256 + col] for row in [0,32), col in [0,256)
    #pragma unroll
    for (int k = 0; k < 8; ++k) {
        int idx = tid + k * 1024;
        int row = idx >> 8;     // 0..31
        int col = idx & 255;
        out[(size_t)row * OUT_SIZE + (q << 8) + col] = acc[col * 33 + row];
    }
}

// ---------------- fallback: direct atomic scatter ----------------
__global__ void zero_f4(float4* __restrict__ p, int n4) {
    int i = blockIdx.x * blockDim.x + threadIdx.x;
    if (i < n4) p[i] = make_float4(0.f, 0.f, 0.f, 0.f);
}
__global__ void scatter_direct(const float* __restrict__ x,
                               const float* __restrict__ w,
                               const int*   __restrict__ dst,
                               const int*   __restrict__ src,
                               float*       __restrict__ out,
                               int nnz) {
    int t = blockIdx.x * blockDim.x + threadIdx.x;
    int e = t >> 5;
    int b = t & 31;
    if (e < nnz) {
        atomicAdd(&out[(size_t)b * OUT_SIZE + dst[e]],
                  w[e] * x[(size_t)b * IN_SIZE + src[e]]);
    }
}

extern "C" void kernel_launch(void* const* d_in, const int* in_sizes, int n_in,
                              void* d_out, int out_size, void* d_ws, size_t ws_size,
                              hipStream_t stream) {
    const float* x   = (const float*)d_in[0];   // [32][65536]
    const float* w   = (const float*)d_in[1];   // [NNZ]
    const int*   dst = (const int*)d_in[2];     // [NNZ]
    const int*   src = (const int*)d_in[3];     // [NNZ]
    float*       out = (float*)d_out;           // [32][65536]
    const int nnz = in_sizes[1];

    // workspace layout (13 MiB)
    const size_t XT_OFF   = 0;                       // bf16 xt: 4 MiB
    const size_t GOFF_OFF = (size_t)4 << 20;         // 65537 ints (~256KB)
    const size_t BH_OFF   = ((size_t)4 << 20) + ((size_t)512 << 10);  // 256KB
    const size_t META_OFF = (size_t)5 << 20;         // 4 MiB
    const size_t WF_OFF   = (size_t)9 << 20;         // 4 MiB
    const size_t WS_NEEDED = (size_t)13 << 20;

    if (ws_size >= WS_NEEDED && nnz <= (1 << 20)) {
        __hip_bfloat16* xt   = (__hip_bfloat16*)((char*)d_ws + XT_OFF);
        int*            goff = (int*)  ((char*)d_ws + GOFF_OFF);
        int*            bh   = (int*)  ((char*)d_ws + BH_OFF);
        uint*           meta = (uint*) ((char*)d_ws + META_OFF);
        float*          wf   = (float*)((char*)d_ws + WF_OFF);

        const int epb = (nnz + NBLK - 1) / NBLK;   // edges per partition block

        transpose_in_bf16<<<IN_SIZE / 32, 1024, 0, stream>>>(x, xt);
        hist_part<<<NBLK, 256, 0, stream>>>(dst, bh, nnz, epb);
        scan_hist<<<1, 1024, 0, stream>>>(bh, goff);
        partition_edges<<<NBLK, 256, 0, stream>>>(dst, src, w, goff, meta, wf, nnz, epb);
        accum_bucket<<<NBKT, 1024, 0, stream>>>(xt, meta, wf, goff, out);
    } else {
        // fallback: zero d_out, atomics in native layout
        int n4 = out_size / 4;
        zero_f4<<<(n4 + 255) / 256, 256, 0, stream>>>((float4*)d_out, n4);
        long long total = (long long)nnz * 32;
        int blocks = (int)((total + 255) / 256);
        scatter_direct<<<blocks, 256, 0, stream>>>(x, w, dst, src, out, nnz);
    }
}

// Round 4
// 227.895 us; speedup vs baseline: 1.0148x; 1.0148x over previous
//
#include <hip/hip_runtime.h>
#include <hip/hip_bf16.h>

// DenSparse: out[b, dst_e] += w_e * x[b, src_e]
// B=32, IN=OUT=65536, NNZ=1048576
//
// Round 4: fix accum_bucket latency-bound serialization (round 3: 181us,
// VALUBusy 4%, 1 block/CU, 1 edge per half-wave-iter in a dependent chain).
//  - 512 buckets (dst>>7): LDS acc = 128x33 f32 = 16.9KB -> 2 blocks/CU,
//    32 waves/CU.
//  - edge record = uint2 {src|d7<<16, w_bits}: one aligned 8B broadcast load.
//  - 8 edges per half-wave iteration: 8 record loads, 8 independent gathers
//    in flight, 8 ds_add_f32 (fire-and-forget). Static unroll.

#define IN_SIZE  65536
#define OUT_SIZE 65536
#define BATCH    32
#define NBLK     128      // partition blocks
#define NBKT     512      // buckets (dst >> 7)

typedef unsigned int uint;
typedef unsigned short ushort;

__device__ __forceinline__ float bf2f(ushort v) {
    return __uint_as_float((uint)v << 16);
}

// ---------------- x[32][IN] -> xt_bf16[IN][32] ----------------
__global__ void transpose_in_bf16(const float* __restrict__ x,
                                  ushort* __restrict__ xt) {
    __shared__ float tile[32][33];
    int i0 = blockIdx.x * 32;
    int tx = threadIdx.x & 31;
    int ty = threadIdx.x >> 5;
    tile[ty][tx] = x[(size_t)ty * IN_SIZE + i0 + tx];
    __syncthreads();
    __hip_bfloat16 h = __float2bfloat16(tile[tx][ty]);
    xt[((size_t)(i0 + ty)) * BATCH + tx] = *(ushort*)&h;
}

// ---------------- pass A: per-block histogram of dst>>7 ----------------
__global__ void hist_part(const int* __restrict__ dst, int* __restrict__ bhist,
                          int nnz, int epb) {
    __shared__ int h[NBKT];
    int blk = blockIdx.x, tid = threadIdx.x;   // 512 threads
    h[tid] = 0;
    __syncthreads();
    int base = blk * epb;
    int lim  = min(nnz, base + epb);
    for (int e = base + tid; e < lim; e += 512)
        atomicAdd(&h[dst[e] >> 7], 1);
    __syncthreads();
    // bucket-major: bhist[q*NBLK + blk]
    bhist[(tid << 7) | blk] = h[tid];
}

// ---------------- pass B: exclusive scan of 65536 counters ----------------
// single WG, 1024 threads x 64. goff has 65537 entries, goff[65536] = nnz.
__global__ void scan_hist(const int* __restrict__ bhist, int* __restrict__ goff) {
    __shared__ int sums[1024];
    const int tid  = threadIdx.x;
    const int base = tid * 64;
    const int4* c4 = (const int4*)(bhist + base);
    int4 v[16];
    int lsum = 0;
    #pragma unroll
    for (int j = 0; j < 16; ++j) {
        v[j] = c4[j];
        lsum += v[j].x + v[j].y + v[j].z + v[j].w;
    }
    sums[tid] = lsum;
    __syncthreads();
    for (int ofs = 1; ofs < 1024; ofs <<= 1) {
        int t = (tid >= ofs) ? sums[tid - ofs] : 0;
        __syncthreads();
        sums[tid] += t;
        __syncthreads();
    }
    int run = sums[tid] - lsum;
    #pragma unroll
    for (int j = 0; j < 16; ++j) {
        goff[base + j * 4 + 0] = run; run += v[j].x;
        goff[base + j * 4 + 1] = run; run += v[j].y;
        goff[base + j * 4 + 2] = run; run += v[j].z;
        goff[base + j * 4 + 3] = run; run += v[j].w;
    }
    if (tid == 1023) goff[NBKT * NBLK] = run;   // == nnz
}

// ---------------- pass C: partition edges into uint2 records ----------------
__global__ void partition_edges(const int* __restrict__ dst,
                                const int* __restrict__ src,
                                const float* __restrict__ w,
                                const int* __restrict__ goff,
                                uint2* __restrict__ rec,
                                int nnz, int epb) {
    __shared__ int cur[NBKT];
    int blk = blockIdx.x, tid = threadIdx.x;   // 512 threads
    cur[tid] = goff[(tid << 7) | blk];
    __syncthreads();
    int base = blk * epb;
    int lim  = min(nnz, base + epb);
    for (int e = base + tid; e < lim; e += 512) {
        int d = dst[e];
        int pos = atomicAdd(&cur[d >> 7], 1);   // run is block-private
        rec[pos] = make_uint2((uint)(src[e] & 0xFFFF) | ((uint)(d & 127) << 16),
                              __float_as_uint(w[e]));
    }
}

// ---------------- pass D: per-bucket accumulate, 8-deep pipeline ----------------
__global__ __launch_bounds__(1024, 8) void accum_bucket(
        const ushort* __restrict__ xt,
        const uint2*  __restrict__ rec,
        const int*    __restrict__ goff,
        float* __restrict__ out) {
    __shared__ float acc[128 * 33];   // [dst_low7][batch], 33-stride
    const int q   = blockIdx.x;
    const int tid = threadIdx.x;
    #pragma unroll
    for (int k = 0; k < 5; ++k) {
        int i = tid + k * 1024;
        if (i < 128 * 33) acc[i] = 0.f;
    }
    __syncthreads();
    const int beg = goff[q << 7];
    const int end = goff[(q + 1) << 7];
    const int hw  = tid >> 5;    // 0..31
    const int b   = tid & 31;
    const int n   = end - beg;
    const int nfull = n & ~(32 * 8 - 1);   // multiple of 256

    for (int i0 = beg + hw * 8; i0 < beg + nfull; i0 += 32 * 8) {
        uint2 r[8];
        #pragma unroll
        for (int j = 0; j < 8; ++j) r[j] = rec[i0 + j];   // 8B broadcast loads
        float xv[8];
        #pragma unroll
        for (int j = 0; j < 8; ++j)
            xv[j] = bf2f(xt[(r[j].x & 0xFFFFu) * BATCH + b]);  // 8 gathers in flight
        #pragma unroll
        for (int j = 0; j < 8; ++j)
            atomicAdd(&acc[((r[j].x >> 16) & 127u) * 33 + b],
                      __uint_as_float(r[j].y) * xv[j]);        // ds_add_f32
    }
    // tail
    for (int i = beg + nfull + hw; i < end; i += 32) {
        uint2 r = rec[i];
        float xv = bf2f(xt[(r.x & 0xFFFFu) * BATCH + b]);
        atomicAdd(&acc[((r.x >> 16) & 127u) * 33 + b],
                  __uint_as_float(r.y) * xv);
    }
    __syncthreads();
    // out[row][q*128 + col], 4 elems/thread, coalesced along col
    #pragma unroll
    for (int k = 0; k < 4; ++k) {
        int idx = tid + k * 1024;
        int row = idx >> 7;     // 0..31
        int col = idx & 127;
        out[(size_t)row * OUT_SIZE + (q << 7) + col] = acc[col * 33 + row];
    }
}

// ---------------- fallback ----------------
__global__ void zero_f4(float4* __restrict__ p, int n4) {
    int i = blockIdx.x * blockDim.x + threadIdx.x;
    if (i < n4) p[i] = make_float4(0.f, 0.f, 0.f, 0.f);
}
__global__ void scatter_direct(const float* __restrict__ x,
                               const float* __restrict__ w,
                               const int*   __restrict__ dst,
                               const int*   __restrict__ src,
                               float*       __restrict__ out,
                               int nnz) {
    int t = blockIdx.x * blockDim.x + threadIdx.x;
    int e = t >> 5;
    int b = t & 31;
    if (e < nnz) {
        atomicAdd(&out[(size_t)b * OUT_SIZE + dst[e]],
                  w[e] * x[(size_t)b * IN_SIZE + src[e]]);
    }
}

extern "C" void kernel_launch(void* const* d_in, const int* in_sizes, int n_in,
                              void* d_out, int out_size, void* d_ws, size_t ws_size,
                              hipStream_t stream) {
    const float* x   = (const float*)d_in[0];   // [32][65536]
    const float* w   = (const float*)d_in[1];   // [NNZ]
    const int*   dst = (const int*)d_in[2];     // [NNZ]
    const int*   src = (const int*)d_in[3];     // [NNZ]
    float*       out = (float*)d_out;           // [32][65536]
    const int nnz = in_sizes[1];

    // workspace layout (13 MiB)
    const size_t XT_OFF   = 0;                                        // 4 MiB
    const size_t GOFF_OFF = (size_t)4 << 20;                          // 256KB+4
    const size_t BH_OFF   = ((size_t)4 << 20) + ((size_t)512 << 10);  // 256KB
    const size_t REC_OFF  = (size_t)5 << 20;                          // 8 MiB
    const size_t WS_NEEDED = (size_t)13 << 20;

    if (ws_size >= WS_NEEDED && nnz <= (1 << 20)) {
        ushort* xt   = (ushort*)((char*)d_ws + XT_OFF);
        int*    goff = (int*)   ((char*)d_ws + GOFF_OFF);
        int*    bh   = (int*)   ((char*)d_ws + BH_OFF);
        uint2*  rec  = (uint2*) ((char*)d_ws + REC_OFF);

        const int epb = (nnz + NBLK - 1) / NBLK;

        transpose_in_bf16<<<IN_SIZE / 32, 1024, 0, stream>>>(x, xt);
        hist_part<<<NBLK, NBKT, 0, stream>>>(dst, bh, nnz, epb);
        scan_hist<<<1, 1024, 0, stream>>>(bh, goff);
        partition_edges<<<NBLK, NBKT, 0, stream>>>(dst, src, w, goff, rec, nnz, epb);
        accum_bucket<<<NBKT, 1024, 0, stream>>>(xt, rec, goff, out);
    } else {
        int n4 = out_size / 4;
        zero_f4<<<(n4 + 255) / 256, 256, 0, stream>>>((float4*)d_out, n4);
        long long total = (long long)nnz * 32;
        int blocks = (int)((total + 255) / 256);
        scatter_direct<<<blocks, 256, 0, stream>>>(x, w, dst, src, out, nnz);
    }
}

// Round 5
// 80.152 us; speedup vs baseline: 2.8854x; 2.8433x over previous
//
#include <hip/hip_runtime.h>
#include <hip/hip_bf16.h>

// DenSparse: out[b, dst_e] += w_e * x[b, src_e]
// B=32, IN=OUT=65536, NNZ=1048576
//
// Round 5: r3/r4's accum (LDS f32 atomics + ushort gathers) was stuck at
// 180us regardless of ILP/TLP => suspected sub-dword gather / ds_add_f32
// throughput wall. Replace with atomic-free CSR accumulate:
//   per-bucket WG: load records -> LDS, counting-sort by local dst in LDS,
//   half-wave owns 4 dsts, serial f32 register accumulation with 4-wide
//   pipelined f32 dword gathers, coalesced slab write. No float atomics
//   anywhere; all global writes dense.
// xt back to f32 (dword gathers); w stored as bf16 to fit 14.25MB workspace.

#define IN_SIZE  65536
#define OUT_SIZE 65536
#define BATCH    32
#define NBLK     128      // partition blocks
#define NBKT     512      // buckets (dst >> 7)
#define CHUNK    2560     // records per LDS chunk in accum

typedef unsigned int uint;
typedef unsigned short ushort;

// ---------------- x[32][IN] -> xt_f32[IN][32] ----------------
__global__ void transpose_in(const float* __restrict__ x, float* __restrict__ xt) {
    __shared__ float tile[32][33];
    int i0 = blockIdx.x * 32;
    int tx = threadIdx.x & 31;
    int ty = threadIdx.x >> 5;
    tile[ty][tx] = x[(size_t)ty * IN_SIZE + i0 + tx];
    __syncthreads();
    xt[((size_t)(i0 + ty)) * BATCH + tx] = tile[tx][ty];
}

// ---------------- pass A: per-block histogram of dst>>7 into goff ----------------
__global__ void hist_part(const int* __restrict__ dst, int* __restrict__ goff,
                          int nnz, int epb) {
    __shared__ int h[NBKT];
    int blk = blockIdx.x, tid = threadIdx.x;   // 512 threads
    h[tid] = 0;
    __syncthreads();
    int base = blk * epb;
    int lim  = min(nnz, base + epb);
    for (int e = base + tid; e < lim; e += 512)
        atomicAdd(&h[dst[e] >> 7], 1);
    __syncthreads();
    goff[(tid << 7) | blk] = h[tid];   // bucket-major: goff[q*NBLK + blk]
}

// ---------------- pass B: in-place exclusive scan of goff[65536] ----------------
// Single WG, 1024 threads x 64 elems. Each thread reads its own range into
// registers BEFORE the scan barriers, writes only its own range after -> safe
// in-place. goff[65536] = nnz afterwards.
__global__ void scan_hist(int* __restrict__ goff) {
    __shared__ int sums[1024];
    const int tid  = threadIdx.x;
    const int base = tid * 64;
    int4* c4 = (int4*)(goff + base);
    int4 v[16];
    int lsum = 0;
    #pragma unroll
    for (int j = 0; j < 16; ++j) {
        v[j] = c4[j];
        lsum += v[j].x + v[j].y + v[j].z + v[j].w;
    }
    sums[tid] = lsum;
    __syncthreads();
    for (int ofs = 1; ofs < 1024; ofs <<= 1) {
        int t = (tid >= ofs) ? sums[tid - ofs] : 0;
        __syncthreads();
        sums[tid] += t;
        __syncthreads();
    }
    int run = sums[tid] - lsum;
    #pragma unroll
    for (int j = 0; j < 16; ++j) {
        goff[base + j * 4 + 0] = run; run += v[j].x;
        goff[base + j * 4 + 1] = run; run += v[j].y;
        goff[base + j * 4 + 2] = run; run += v[j].z;
        goff[base + j * 4 + 3] = run; run += v[j].w;
    }
    if (tid == 1023) goff[NBKT * NBLK] = run;   // == nnz
}

// ---------------- pass C: partition into meta(u32) + wq(bf16) ----------------
__global__ void partition_edges(const int* __restrict__ dst,
                                const int* __restrict__ src,
                                const float* __restrict__ w,
                                const int* __restrict__ goff,
                                uint*   __restrict__ meta,
                                ushort* __restrict__ wq,
                                int nnz, int epb) {
    __shared__ int cur[NBKT];
    int blk = blockIdx.x, tid = threadIdx.x;   // 512 threads
    cur[tid] = goff[(tid << 7) | blk];
    __syncthreads();
    int base = blk * epb;
    int lim  = min(nnz, base + epb);
    for (int e = base + tid; e < lim; e += 512) {
        int d = dst[e];
        int pos = atomicAdd(&cur[d >> 7], 1);   // run is block-private => dense
        meta[pos] = (uint)(src[e] & 0xFFFF) | ((uint)(d & 127) << 16);
        __hip_bfloat16 h = __float2bfloat16(w[e]);
        wq[pos] = *(ushort*)&h;
    }
}

// ---------------- pass D: in-LDS counting sort + CSR register accumulate ----------------
__global__ __launch_bounds__(1024, 8) void accum_sort_csr(
        const float*  __restrict__ xt,
        const uint*   __restrict__ meta,
        const ushort* __restrict__ wq,
        const int*    __restrict__ goff,
        float* __restrict__ out) {
    __shared__ uint2 bufA[CHUNK];   // raw records {meta, w_f32_bits}; reused as out-stage
    __shared__ uint2 bufB[CHUNK];   // dst-sorted records
    __shared__ int   soff[129];     // local CSR offsets
    __shared__ int   scnt[128];     // counters, then cursors
    __shared__ int   sS[128];       // scan workspace

    const int q   = blockIdx.x;
    const int tid = threadIdx.x;
    const int hw  = tid >> 5;       // half-wave 0..31
    const int b   = tid & 31;       // batch lane
    const int beg = goff[q << 7];
    const int end = goff[(q + 1) << 7];   // q=511 -> goff[65536] = nnz

    float acc0 = 0.f, acc1 = 0.f, acc2 = 0.f, acc3 = 0.f;

    for (int cbeg = beg; cbeg < end; cbeg += CHUNK) {
        const int n = min(CHUNK, end - cbeg);
        if (tid < 128) scnt[tid] = 0;
        __syncthreads();
        // load records into LDS (w converted bf16->f32 bits once) + count
        for (int j = tid; j < n; j += 1024) {
            uint m  = meta[cbeg + j];
            uint wb = (uint)wq[cbeg + j] << 16;   // bf16 -> f32 bits
            bufA[j] = make_uint2(m, wb);
            atomicAdd(&scnt[(m >> 16) & 127u], 1);
        }
        __syncthreads();
        // exclusive scan of 128 counts (Hillis-Steele, 7 steps)
        int own = 0;
        if (tid < 128) { own = scnt[tid]; sS[tid] = own; }
        __syncthreads();
        #pragma unroll
        for (int ofs = 1; ofs < 128; ofs <<= 1) {
            int v = 0;
            if (tid < 128 && tid >= ofs) v = sS[tid - ofs];
            __syncthreads();
            if (tid < 128) sS[tid] += v;
            __syncthreads();
        }
        if (tid < 128) {
            int excl = sS[tid] - own;
            soff[tid] = excl;
            scnt[tid] = excl;                    // cursor for scatter
            if (tid == 127) soff[128] = sS[127]; // == n
        }
        __syncthreads();
        // scatter A -> B (dst-sorted within chunk)
        for (int j = tid; j < n; j += 1024) {
            uint2 r = bufA[j];
            int pos = atomicAdd(&scnt[(r.x >> 16) & 127u], 1);
            bufB[pos] = r;
        }
        __syncthreads();
        // CSR accumulate: half-wave hw owns local dsts hw, 32+hw, 64+hw, 96+hw.
        // 4-wide batching: 4 LDS rec reads -> 4 independent dword gathers -> 4 FMAs.
        #define DO_DST(T, ACC) { \
            int d  = ((T) << 5) + hw; \
            int i  = soff[d], e2 = soff[d + 1]; \
            for (; i + 4 <= e2; i += 4) { \
                uint2 r0 = bufB[i], r1 = bufB[i+1], r2 = bufB[i+2], r3 = bufB[i+3]; \
                float g0 = xt[(r0.x & 0xFFFFu) * BATCH + b]; \
                float g1 = xt[(r1.x & 0xFFFFu) * BATCH + b]; \
                float g2 = xt[(r2.x & 0xFFFFu) * BATCH + b]; \
                float g3 = xt[(r3.x & 0xFFFFu) * BATCH + b]; \
                ACC += __uint_as_float(r0.y) * g0; \
                ACC += __uint_as_float(r1.y) * g1; \
                ACC += __uint_as_float(r2.y) * g2; \
                ACC += __uint_as_float(r3.y) * g3; \
            } \
            for (; i < e2; ++i) { \
                uint2 r = bufB[i]; \
                ACC += __uint_as_float(r.y) * xt[(r.x & 0xFFFFu) * BATCH + b]; \
            } \
        }
        DO_DST(0, acc0)
        DO_DST(1, acc1)
        DO_DST(2, acc2)
        DO_DST(3, acc3)
        #undef DO_DST
        __syncthreads();   // bufA/bufB dead before next chunk reload
    }

    // stage accumulators -> LDS (reuse bufA: 128*33*4B = 16.9KB <= 20KB), write slab
    float* stg = (float*)bufA;
    stg[(hw +  0) * 33 + b] = acc0;
    stg[(hw + 32) * 33 + b] = acc1;
    stg[(hw + 64) * 33 + b] = acc2;
    stg[(hw + 96) * 33 + b] = acc3;
    __syncthreads();
    #pragma unroll
    for (int k = 0; k < 4; ++k) {
        int idx = tid + (k << 10);
        int row = idx >> 7;    // 0..31
        int col = idx & 127;
        out[(size_t)row * OUT_SIZE + (q << 7) + col] = stg[col * 33 + row];
    }
}

// ---------------- fallback ----------------
__global__ void zero_f4(float4* __restrict__ p, int n4) {
    int i = blockIdx.x * blockDim.x + threadIdx.x;
    if (i < n4) p[i] = make_float4(0.f, 0.f, 0.f, 0.f);
}
__global__ void scatter_direct(const float* __restrict__ x,
                               const float* __restrict__ w,
                               const int*   __restrict__ dst,
                               const int*   __restrict__ src,
                               float*       __restrict__ out,
                               int nnz) {
    int t = blockIdx.x * blockDim.x + threadIdx.x;
    int e = t >> 5;
    int b = t & 31;
    if (e < nnz) {
        atomicAdd(&out[(size_t)b * OUT_SIZE + dst[e]],
                  w[e] * x[(size_t)b * IN_SIZE + src[e]]);
    }
}

extern "C" void kernel_launch(void* const* d_in, const int* in_sizes, int n_in,
                              void* d_out, int out_size, void* d_ws, size_t ws_size,
                              hipStream_t stream) {
    const float* x   = (const float*)d_in[0];   // [32][65536]
    const float* w   = (const float*)d_in[1];   // [NNZ]
    const int*   dst = (const int*)d_in[2];     // [NNZ]
    const int*   src = (const int*)d_in[3];     // [NNZ]
    float*       out = (float*)d_out;           // [32][65536]
    const int nnz = in_sizes[1];

    // workspace layout (14.25 MiB + eps)
    const size_t XT_OFF   = 0;                        // f32 xt: 8 MiB
    const size_t META_OFF = (size_t)8 << 20;          // u32 meta: 4 MiB
    const size_t WQ_OFF   = (size_t)12 << 20;         // bf16 w: 2 MiB
    const size_t GOFF_OFF = (size_t)14 << 20;         // 65537 ints
    const size_t WS_NEEDED = ((size_t)14 << 20) + 65537 * 4;

    if (ws_size >= WS_NEEDED && nnz <= (1 << 20)) {
        float*  xt   = (float*) ((char*)d_ws + XT_OFF);
        uint*   meta = (uint*)  ((char*)d_ws + META_OFF);
        ushort* wq   = (ushort*)((char*)d_ws + WQ_OFF);
        int*    goff = (int*)   ((char*)d_ws + GOFF_OFF);

        const int epb = (nnz + NBLK - 1) / NBLK;

        transpose_in<<<IN_SIZE / 32, 1024, 0, stream>>>(x, xt);
        hist_part<<<NBLK, NBKT, 0, stream>>>(dst, goff, nnz, epb);
        scan_hist<<<1, 1024, 0, stream>>>(goff);
        partition_edges<<<NBLK, NBKT, 0, stream>>>(dst, src, w, goff, meta, wq, nnz, epb);
        accum_sort_csr<<<NBKT, 1024, 0, stream>>>(xt, meta, wq, goff, out);
    } else {
        int n4 = out_size / 4;
        zero_f4<<<(n4 + 255) / 256, 256, 0, stream>>>((float4*)d_out, n4);
        long long total = (long long)nnz * 32;
        int blocks = (int)((total + 255) / 256);
        scatter_direct<<<blocks, 256, 0, stream>>>(x, w, dst, src, out, nnz);
    }
}

// Round 6
// 58.915 us; speedup vs baseline: 3.9255x; 1.3605x over previous
//
#include <hip/hip_runtime.h>
#include <hip/hip_bf16.h>

// DenSparse: out[b, dst_e] += w_e * x[b, src_e]
// B=32, IN=OUT=65536, NNZ=1048576
//
// Round 6: fuse hist+scan+partition (3 passes, ~30us, incl. single-WG 64K
// scan) into ONE pass via atomic range reservation into fixed-capacity
// bucket regions (CAP=2560/bucket; count ~ Binomial(1M,1/512): mean 2048,
// sigma 45 -> overflow probability ~1e-28). Each block keeps its 8192 edges
// in REGISTERS (8/thread, static unroll), LDS-counts 512 buckets, reserves
// per-bucket ranges with one global atomicAdd per (block,bucket), scatters
// dense runs. Accum = round-5's proven in-LDS counting-sort + CSR register
// accumulate, now single-chunk (n <= CAP).

#define IN_SIZE  65536
#define OUT_SIZE 65536
#define BATCH    32
#define NBKT     512      // buckets (dst >> 7)
#define CAP      2560     // per-bucket region capacity
#define EPB      8192     // edges per partition block (1024 thr x 8)

typedef unsigned int uint;
typedef unsigned short ushort;

// ---------------- zero bucket counters ----------------
__global__ void zero_cnt(int* __restrict__ g) { g[threadIdx.x] = 0; }

// ---------------- x[32][IN] -> xt_f32[IN][32] ----------------
__global__ void transpose_in(const float* __restrict__ x, float* __restrict__ xt) {
    __shared__ float tile[32][33];
    int i0 = blockIdx.x * 32;
    int tx = threadIdx.x & 31;
    int ty = threadIdx.x >> 5;
    tile[ty][tx] = x[(size_t)ty * IN_SIZE + i0 + tx];
    __syncthreads();
    xt[((size_t)(i0 + ty)) * BATCH + tx] = tile[tx][ty];
}

// ---------------- fused count + reserve + scatter ----------------
// meta word m = src16 | (dst16 << 16): bucket = m>>23, local dst = (m>>16)&127.
__global__ __launch_bounds__(1024) void part_fused(
        const int* __restrict__ dst, const int* __restrict__ src,
        const float* __restrict__ w, int* __restrict__ gcnt,
        uint* __restrict__ meta, ushort* __restrict__ wq, int nnz) {
    __shared__ int cnt[NBKT];
    __shared__ int curs[NBKT];
    const int tid = threadIdx.x;
    if (tid < NBKT) cnt[tid] = 0;
    __syncthreads();

    const int e0 = blockIdx.x * EPB + tid * 8;
    uint  m[8];
    float wv[8];
    bool  val[8];
    if (e0 + 8 <= nnz) {
        int4 da = *(const int4*)(dst + e0), db = *(const int4*)(dst + e0 + 4);
        int4 sa = *(const int4*)(src + e0), sb = *(const int4*)(src + e0 + 4);
        float4 wa = *(const float4*)(w + e0), wb = *(const float4*)(w + e0 + 4);
        m[0] = (uint)(sa.x & 0xFFFF) | ((uint)da.x << 16); wv[0] = wa.x;
        m[1] = (uint)(sa.y & 0xFFFF) | ((uint)da.y << 16); wv[1] = wa.y;
        m[2] = (uint)(sa.z & 0xFFFF) | ((uint)da.z << 16); wv[2] = wa.z;
        m[3] = (uint)(sa.w & 0xFFFF) | ((uint)da.w << 16); wv[3] = wa.w;
        m[4] = (uint)(sb.x & 0xFFFF) | ((uint)db.x << 16); wv[4] = wb.x;
        m[5] = (uint)(sb.y & 0xFFFF) | ((uint)db.y << 16); wv[5] = wb.y;
        m[6] = (uint)(sb.z & 0xFFFF) | ((uint)db.z << 16); wv[6] = wb.z;
        m[7] = (uint)(sb.w & 0xFFFF) | ((uint)db.w << 16); wv[7] = wb.w;
        #pragma unroll
        for (int j = 0; j < 8; ++j) val[j] = true;
    } else {
        #pragma unroll
        for (int j = 0; j < 8; ++j) {
            int e = e0 + j;
            val[j] = (e < nnz);
            m[j]  = val[j] ? ((uint)(src[e] & 0xFFFF) | ((uint)dst[e] << 16)) : 0u;
            wv[j] = val[j] ? w[e] : 0.f;
        }
    }
    #pragma unroll
    for (int j = 0; j < 8; ++j)
        if (val[j]) atomicAdd(&cnt[m[j] >> 23], 1);
    __syncthreads();
    // reserve this block's range in each bucket region
    if (tid < NBKT) curs[tid] = atomicAdd(&gcnt[tid], cnt[tid]);
    __syncthreads();
    // scatter: dense ~16-edge runs per (block,bucket)
    #pragma unroll
    for (int j = 0; j < 8; ++j) {
        if (val[j]) {
            uint q = m[j] >> 23;
            int pos = atomicAdd(&curs[q], 1);
            if (pos < CAP) {   // statistically unreachable guard
                size_t idx = (size_t)q * CAP + pos;
                meta[idx] = m[j];
                __hip_bfloat16 h = __float2bfloat16(wv[j]);
                wq[idx] = *(ushort*)&h;
            }
        }
    }
}

// ---------------- per-bucket: in-LDS counting sort + CSR register accumulate ----------------
__global__ __launch_bounds__(1024, 8) void accum_sort_csr(
        const float*  __restrict__ xt,
        const uint*   __restrict__ meta,
        const ushort* __restrict__ wq,
        const int*    __restrict__ gcnt,
        float* __restrict__ out) {
    __shared__ uint2 bufA[CAP];   // raw records; reused as output stage
    __shared__ uint2 bufB[CAP];   // dst-sorted records
    __shared__ int   soff[129];
    __shared__ int   scnt[128];
    __shared__ int   sS[128];

    const int q   = blockIdx.x;
    const int tid = threadIdx.x;
    const int hw  = tid >> 5;     // half-wave 0..31
    const int b   = tid & 31;     // batch lane
    const int n   = min(gcnt[q], CAP);
    const size_t beg = (size_t)q * CAP;

    if (tid < 128) scnt[tid] = 0;
    __syncthreads();
    // load records (bf16 w -> f32 bits once) + per-local-dst count
    for (int j = tid; j < n; j += 1024) {
        uint mm = meta[beg + j];
        uint wb = (uint)wq[beg + j] << 16;
        bufA[j] = make_uint2(mm, wb);
        atomicAdd(&scnt[(mm >> 16) & 127u], 1);
    }
    __syncthreads();
    // exclusive scan of 128 counts
    int own = 0;
    if (tid < 128) { own = scnt[tid]; sS[tid] = own; }
    __syncthreads();
    #pragma unroll
    for (int ofs = 1; ofs < 128; ofs <<= 1) {
        int v = 0;
        if (tid < 128 && tid >= ofs) v = sS[tid - ofs];
        __syncthreads();
        if (tid < 128) sS[tid] += v;
        __syncthreads();
    }
    if (tid < 128) {
        int excl = sS[tid] - own;
        soff[tid] = excl;
        scnt[tid] = excl;                    // cursor
        if (tid == 127) soff[128] = sS[127]; // == n
    }
    __syncthreads();
    // scatter A -> B (sorted by local dst)
    for (int j = tid; j < n; j += 1024) {
        uint2 r = bufA[j];
        int pos = atomicAdd(&scnt[(r.x >> 16) & 127u], 1);
        bufB[pos] = r;
    }
    __syncthreads();
    // CSR accumulate: half-wave hw owns local dsts hw, 32+hw, 64+hw, 96+hw
    float acc0 = 0.f, acc1 = 0.f, acc2 = 0.f, acc3 = 0.f;
    #define DO_DST(T, ACC) { \
        int d  = ((T) << 5) + hw; \
        int i  = soff[d], e2 = soff[d + 1]; \
        for (; i + 4 <= e2; i += 4) { \
            uint2 r0 = bufB[i], r1 = bufB[i+1], r2 = bufB[i+2], r3 = bufB[i+3]; \
            float g0 = xt[(r0.x & 0xFFFFu) * BATCH + b]; \
            float g1 = xt[(r1.x & 0xFFFFu) * BATCH + b]; \
            float g2 = xt[(r2.x & 0xFFFFu) * BATCH + b]; \
            float g3 = xt[(r3.x & 0xFFFFu) * BATCH + b]; \
            ACC += __uint_as_float(r0.y) * g0; \
            ACC += __uint_as_float(r1.y) * g1; \
            ACC += __uint_as_float(r2.y) * g2; \
            ACC += __uint_as_float(r3.y) * g3; \
        } \
        for (; i < e2; ++i) { \
            uint2 r = bufB[i]; \
            ACC += __uint_as_float(r.y) * xt[(r.x & 0xFFFFu) * BATCH + b]; \
        } \
    }
    DO_DST(0, acc0)
    DO_DST(1, acc1)
    DO_DST(2, acc2)
    DO_DST(3, acc3)
    #undef DO_DST
    __syncthreads();
    // stage -> coalesced slab write (reuse bufA: 128*33*4B = 16.9KB <= 20KB)
    float* stg = (float*)bufA;
    stg[(hw +  0) * 33 + b] = acc0;
    stg[(hw + 32) * 33 + b] = acc1;
    stg[(hw + 64) * 33 + b] = acc2;
    stg[(hw + 96) * 33 + b] = acc3;
    __syncthreads();
    #pragma unroll
    for (int k = 0; k < 4; ++k) {
        int idx = tid + (k << 10);
        int row = idx >> 7;    // 0..31
        int col = idx & 127;
        out[(size_t)row * OUT_SIZE + (q << 7) + col] = stg[col * 33 + row];
    }
}

// ---------------- fallback ----------------
__global__ void zero_f4(float4* __restrict__ p, int n4) {
    int i = blockIdx.x * blockDim.x + threadIdx.x;
    if (i < n4) p[i] = make_float4(0.f, 0.f, 0.f, 0.f);
}
__global__ void scatter_direct(const float* __restrict__ x,
                               const float* __restrict__ w,
                               const int*   __restrict__ dst,
                               const int*   __restrict__ src,
                               float*       __restrict__ out,
                               int nnz) {
    int t = blockIdx.x * blockDim.x + threadIdx.x;
    int e = t >> 5;
    int b = t & 31;
    if (e < nnz) {
        atomicAdd(&out[(size_t)b * OUT_SIZE + dst[e]],
                  w[e] * x[(size_t)b * IN_SIZE + src[e]]);
    }
}

extern "C" void kernel_launch(void* const* d_in, const int* in_sizes, int n_in,
                              void* d_out, int out_size, void* d_ws, size_t ws_size,
                              hipStream_t stream) {
    const float* x   = (const float*)d_in[0];   // [32][65536]
    const float* w   = (const float*)d_in[1];   // [NNZ]
    const int*   dst = (const int*)d_in[2];     // [NNZ]
    const int*   src = (const int*)d_in[3];     // [NNZ]
    float*       out = (float*)d_out;           // [32][65536]
    const int nnz = in_sizes[1];

    // workspace layout (15.5 MiB + 2KB)
    const size_t XT_OFF   = 0;                                   // 8 MiB
    const size_t META_OFF = (size_t)8 << 20;                     // 5 MiB
    const size_t WQ_OFF   = META_OFF + (size_t)NBKT * CAP * 4;   // 2.5 MiB
    const size_t GCNT_OFF = WQ_OFF + (size_t)NBKT * CAP * 2;     // 2 KB
    const size_t WS_NEEDED = GCNT_OFF + NBKT * 4;

    if (ws_size >= WS_NEEDED && nnz <= (1 << 20)) {
        float*  xt   = (float*) ((char*)d_ws + XT_OFF);
        uint*   meta = (uint*)  ((char*)d_ws + META_OFF);
        ushort* wq   = (ushort*)((char*)d_ws + WQ_OFF);
        int*    gcnt = (int*)   ((char*)d_ws + GCNT_OFF);

        zero_cnt<<<1, NBKT, 0, stream>>>(gcnt);
        transpose_in<<<IN_SIZE / 32, 1024, 0, stream>>>(x, xt);
        part_fused<<<(nnz + EPB - 1) / EPB, 1024, 0, stream>>>(dst, src, w, gcnt,
                                                               meta, wq, nnz);
        accum_sort_csr<<<NBKT, 1024, 0, stream>>>(xt, meta, wq, gcnt, out);
    } else {
        int n4 = out_size / 4;
        zero_f4<<<(n4 + 255) / 256, 256, 0, stream>>>((float4*)d_out, n4);
        long long total = (long long)nnz * 32;
        int blocks = (int)((total + 255) / 256);
        scatter_direct<<<blocks, 256, 0, stream>>>(x, w, dst, src, out, nnz);
    }
}

// Round 7
// 44.556 us; speedup vs baseline: 5.1906x; 1.3223x over previous
//
#include <hip/hip_runtime.h>
#include <hip/hip_bf16.h>

// DenSparse: out[b, dst_e] += w_e * x[b, src_e]
// B=32, IN=OUT=65536, NNZ=1048576
//
// Round 7:
//  - xt stored bf16 [IN][32] (4MB, XCD-L2-resident). Gather = one dword
//    (2 batches) per lane, 16-lane group per edge: halves gather bytes and
//    gather instructions vs f32.
//  - accum: rank-capture counting sort (count-atomic return = rank; no bufA,
//    no cursor pass) + per-dst padding to multiple of 8 (zero-weight pads)
//    so the 8-deep gather pipeline has NO scalar tail.
//  - transpose + partition fused into one kernel (independent block ranges);
//    gcnt zeroed by hipMemsetAsync. 3 enqueues total.

#define IN_SIZE  65536
#define OUT_SIZE 65536
#define BATCH    32
#define NBKT     512      // buckets (dst >> 7)
#define CAP      2560     // per-bucket global region capacity (mean 2048, 11 sigma)
#define EPB      8192     // edges per partition block (1024 thr x 8)
#define PBLK     128      // partition blocks (first in grid)
#define TBLK     2048     // transpose blocks (IN_SIZE/32)
#define PADCAP   3584     // bufB capacity >= CAP + 128*7 = 3456

typedef unsigned int uint;
typedef unsigned short ushort;

__device__ __forceinline__ float bf2f(ushort v) {
    return __uint_as_float((uint)v << 16);
}

// ---------------- fused: partition (blocks 0..127) + transpose (rest) ----------------
__global__ __launch_bounds__(1024) void prep_fused(
        const float* __restrict__ x, ushort* __restrict__ xt,
        const int* __restrict__ dst, const int* __restrict__ src,
        const float* __restrict__ w, int* __restrict__ gcnt,
        uint* __restrict__ meta, float* __restrict__ wf, int nnz) {
    const int tid = threadIdx.x;
    if (blockIdx.x < PBLK) {
        // ---- partition: count w/ rank capture -> reserve -> dense scatter ----
        __shared__ int cnt[NBKT];
        __shared__ int base[NBKT];
        if (tid < NBKT) cnt[tid] = 0;
        __syncthreads();
        const int e0 = blockIdx.x * EPB + tid * 8;
        uint m[8]; float wv[8]; int rk[8]; bool val[8];
        if (e0 + 8 <= nnz) {
            int4 da = *(const int4*)(dst + e0), db = *(const int4*)(dst + e0 + 4);
            int4 sa = *(const int4*)(src + e0), sb = *(const int4*)(src + e0 + 4);
            float4 wa = *(const float4*)(w + e0), wb = *(const float4*)(w + e0 + 4);
            m[0] = (uint)(sa.x & 0xFFFF) | ((uint)da.x << 16); wv[0] = wa.x;
            m[1] = (uint)(sa.y & 0xFFFF) | ((uint)da.y << 16); wv[1] = wa.y;
            m[2] = (uint)(sa.z & 0xFFFF) | ((uint)da.z << 16); wv[2] = wa.z;
            m[3] = (uint)(sa.w & 0xFFFF) | ((uint)da.w << 16); wv[3] = wa.w;
            m[4] = (uint)(sb.x & 0xFFFF) | ((uint)db.x << 16); wv[4] = wb.x;
            m[5] = (uint)(sb.y & 0xFFFF) | ((uint)db.y << 16); wv[5] = wb.y;
            m[6] = (uint)(sb.z & 0xFFFF) | ((uint)db.z << 16); wv[6] = wb.z;
            m[7] = (uint)(sb.w & 0xFFFF) | ((uint)db.w << 16); wv[7] = wb.w;
            #pragma unroll
            for (int j = 0; j < 8; ++j) val[j] = true;
        } else {
            #pragma unroll
            for (int j = 0; j < 8; ++j) {
                int e = e0 + j;
                val[j] = (e < nnz);
                m[j]  = val[j] ? ((uint)(src[e] & 0xFFFF) | ((uint)dst[e] << 16)) : 0u;
                wv[j] = val[j] ? w[e] : 0.f;
            }
        }
        #pragma unroll
        for (int j = 0; j < 8; ++j)
            if (val[j]) rk[j] = atomicAdd(&cnt[m[j] >> 23], 1);
        __syncthreads();
        if (tid < NBKT) base[tid] = atomicAdd(&gcnt[tid], cnt[tid]);
        __syncthreads();
        #pragma unroll
        for (int j = 0; j < 8; ++j) {
            if (val[j]) {
                uint q = m[j] >> 23;
                int pos = base[q] + rk[j];
                if (pos < CAP) {   // statistically unreachable overflow guard
                    size_t idx = (size_t)q * CAP + pos;
                    meta[idx] = m[j];
                    wf[idx]   = wv[j];
                }
            }
        }
    } else {
        // ---- transpose x[32][IN] -> xt_bf16[IN][32] ----
        __shared__ float tile[32][33];
        int i0 = (blockIdx.x - PBLK) * 32;
        int tx = tid & 31, ty = tid >> 5;
        tile[ty][tx] = x[(size_t)ty * IN_SIZE + i0 + tx];
        __syncthreads();
        __hip_bfloat16 h = __float2bfloat16(tile[tx][ty]);
        xt[((size_t)(i0 + ty)) * BATCH + tx] = *(ushort*)&h;
    }
}

// ---------------- per-bucket: rank-sort (8-padded) + 8-deep gather accumulate ----------------
__global__ __launch_bounds__(1024) void accum_sort_csr(
        const ushort* __restrict__ xt,
        const uint*   __restrict__ meta,
        const float*  __restrict__ wf,
        const int*    __restrict__ gcnt,
        float* __restrict__ out) {
    __shared__ uint2 bufB[PADCAP];   // sorted+padded records; reused as out-stage
    __shared__ int   soff[129];      // padded CSR offsets
    __shared__ int   scnt[128];      // counts (rank source)
    __shared__ int   sS[128];        // scan workspace

    const int q   = blockIdx.x;
    const int tid = threadIdx.x;
    const int n   = min(gcnt[q], CAP);
    const size_t beg = (size_t)q * CAP;

    if (tid < 128) scnt[tid] = 0;
    __syncthreads();

    // load records (<=3 per thread, static) + rank capture
    uint  mm[3]; float ww[3]; int rk[3]; bool v[3];
    #pragma unroll
    for (int u = 0; u < 3; ++u) {
        int j = tid + (u << 10);
        v[u] = (j < n);
        if (v[u]) {
            mm[u] = meta[beg + j];
            ww[u] = wf[beg + j];
            rk[u] = atomicAdd(&scnt[(mm[u] >> 16) & 127u], 1);
        }
    }
    __syncthreads();

    // exclusive scan of PADDED counts (ceil(c/8)*8)
    int own = 0;
    if (tid < 128) { own = (scnt[tid] + 7) & ~7; sS[tid] = own; }
    __syncthreads();
    #pragma unroll
    for (int ofs = 1; ofs < 128; ofs <<= 1) {
        int t = 0;
        if (tid < 128 && tid >= ofs) t = sS[tid - ofs];
        __syncthreads();
        if (tid < 128) sS[tid] += t;
        __syncthreads();
    }
    if (tid < 128) {
        soff[tid] = sS[tid] - own;
        if (tid == 127) soff[128] = sS[127];
    }
    __syncthreads();

    // zero padded region, then scatter real records (pads stay w=0)
    const int pn = soff[128];
    for (int j = tid; j < pn; j += 1024) bufB[j] = make_uint2(0u, 0u);
    __syncthreads();
    #pragma unroll
    for (int u = 0; u < 3; ++u) {
        if (v[u]) {
            int d = (mm[u] >> 16) & 127;
            bufB[soff[d] + rk[u]] = make_uint2(mm[u], __float_as_uint(ww[u]));
        }
    }
    __syncthreads();

    // accumulate: 16-lane group per dst, lane k holds batches 2k,2k+1.
    // group gid (0..63) owns local dsts gid and gid+64. Runs are multiples
    // of 8 -> pure 8-deep pipeline, no tail.
    const int gid = tid >> 4;
    const int k   = tid & 15;
    float2 a0 = make_float2(0.f, 0.f), a1 = make_float2(0.f, 0.f);
    #define DO_DST(DD, ACC) { \
        int i = soff[DD], e2 = soff[(DD) + 1]; \
        for (; i < e2; i += 8) { \
            uint2 r[8]; \
            _Pragma("unroll") \
            for (int t = 0; t < 8; ++t) r[t] = bufB[i + t]; \
            uint p[8]; \
            _Pragma("unroll") \
            for (int t = 0; t < 8; ++t) \
                p[t] = *(const uint*)(xt + (r[t].x & 0xFFFFu) * BATCH + (k << 1)); \
            _Pragma("unroll") \
            for (int t = 0; t < 8; ++t) { \
                float wv2 = __uint_as_float(r[t].y); \
                ACC.x += wv2 * bf2f((ushort)(p[t] & 0xFFFFu)); \
                ACC.y += wv2 * bf2f((ushort)(p[t] >> 16)); \
            } \
        } \
    }
    DO_DST(gid, a0)
    DO_DST(gid + 64, a1)
    #undef DO_DST
    __syncthreads();

    // stage (reuse bufB as float stg[128][34]; 17.4KB <= 28KB) + slab write
    float* stg = (float*)bufB;
    *(float2*)&stg[gid * 34 + (k << 1)]        = a0;   // 136B row stride: 8B-aligned
    *(float2*)&stg[(gid + 64) * 34 + (k << 1)] = a1;
    __syncthreads();
    #pragma unroll
    for (int kk = 0; kk < 4; ++kk) {
        int idx = tid + (kk << 10);
        int row = idx >> 7;    // 0..31
        int col = idx & 127;
        out[(size_t)row * OUT_SIZE + (q << 7) + col] = stg[col * 34 + row];
    }
}

// ---------------- fallback ----------------
__global__ void zero_f4(float4* __restrict__ p, int n4) {
    int i = blockIdx.x * blockDim.x + threadIdx.x;
    if (i < n4) p[i] = make_float4(0.f, 0.f, 0.f, 0.f);
}
__global__ void scatter_direct(const float* __restrict__ x,
                               const float* __restrict__ w,
                               const int*   __restrict__ dst,
                               const int*   __restrict__ src,
                               float*       __restrict__ out,
                               int nnz) {
    int t = blockIdx.x * blockDim.x + threadIdx.x;
    int e = t >> 5;
    int b = t & 31;
    if (e < nnz) {
        atomicAdd(&out[(size_t)b * OUT_SIZE + dst[e]],
                  w[e] * x[(size_t)b * IN_SIZE + src[e]]);
    }
}

extern "C" void kernel_launch(void* const* d_in, const int* in_sizes, int n_in,
                              void* d_out, int out_size, void* d_ws, size_t ws_size,
                              hipStream_t stream) {
    const float* x   = (const float*)d_in[0];   // [32][65536]
    const float* w   = (const float*)d_in[1];   // [NNZ]
    const int*   dst = (const int*)d_in[2];     // [NNZ]
    const int*   src = (const int*)d_in[3];     // [NNZ]
    float*       out = (float*)d_out;           // [32][65536]
    const int nnz = in_sizes[1];

    // workspace layout (14 MiB + 2KB)
    const size_t XT_OFF   = 0;                                   // bf16 xt: 4 MiB
    const size_t META_OFF = (size_t)4 << 20;                     // u32:  5 MiB
    const size_t WF_OFF   = META_OFF + (size_t)NBKT * CAP * 4;   // f32:  5 MiB
    const size_t GCNT_OFF = WF_OFF + (size_t)NBKT * CAP * 4;     // 2 KB
    const size_t WS_NEEDED = GCNT_OFF + NBKT * 4;

    if (ws_size >= WS_NEEDED && nnz <= (1 << 20)) {
        ushort* xt   = (ushort*)((char*)d_ws + XT_OFF);
        uint*   meta = (uint*)  ((char*)d_ws + META_OFF);
        float*  wf   = (float*) ((char*)d_ws + WF_OFF);
        int*    gcnt = (int*)   ((char*)d_ws + GCNT_OFF);

        hipMemsetAsync(gcnt, 0, NBKT * sizeof(int), stream);
        prep_fused<<<PBLK + TBLK, 1024, 0, stream>>>(x, xt, dst, src, w,
                                                     gcnt, meta, wf, nnz);
        accum_sort_csr<<<NBKT, 1024, 0, stream>>>(xt, meta, wf, gcnt, out);
    } else {
        int n4 = out_size / 4;
        zero_f4<<<(n4 + 255) / 256, 256, 0, stream>>>((float4*)d_out, n4);
        long long total = (long long)nnz * 32;
        int blocks = (int)((total + 255) / 256);
        scatter_direct<<<blocks, 256, 0, stream>>>(x, w, dst, src, out, nnz);
    }
}

// Round 8
// 41.987 us; speedup vs baseline: 5.5082x; 1.0612x over previous
//
#include <hip/hip_runtime.h>
#include <hip/hip_bf16.h>

// DenSparse: out[b, dst_e] += w_e * x[b, src_e]
// B=32, IN=OUT=65536, NNZ=1048576
//
// Round 8:
//  - accum: WAVE-UNIFORM gather loop. Wave owns 8 dsts sequentially; all 64
//    lanes cooperate on one dst (4 edge-slots x 16 batch-pair lanes); runs
//    padded to multiple of 8 -> identical trip count across the wave, zero
//    intra-wave divergence (r7 lost ~30% of issue slots to max-over-4-groups).
//    Cross-eslot combine via 2x shfl_xor per float.
//  - rec packed uint2{src|dst<<16, w_f32bits}: 1 store in prep, 1 load in accum.
//  - transpose: 32x128 slab per block, float4 global loads, ushort4 stores.

#define IN_SIZE  65536
#define OUT_SIZE 65536
#define BATCH    32
#define NBKT     512      // buckets (dst >> 7)
#define CAP      2560     // per-bucket region capacity (mean 2048, 11 sigma)
#define EPB      8192     // edges per partition block (1024 thr x 8)
#define PBLK     128      // partition blocks (first in grid)
#define TBLK     512      // transpose blocks (IN_SIZE/128)
#define PADCAP   3456     // >= CAP + 128*7

typedef unsigned int uint;
typedef unsigned short ushort;

__device__ __forceinline__ float bf2f(ushort v) {
    return __uint_as_float((uint)v << 16);
}

// ---------------- fused: partition (blocks 0..127) + transpose (rest) ----------------
__global__ __launch_bounds__(1024) void prep_fused(
        const float* __restrict__ x, ushort* __restrict__ xt,
        const int* __restrict__ dst, const int* __restrict__ src,
        const float* __restrict__ w, int* __restrict__ gcnt,
        uint2* __restrict__ rec, int nnz) {
    const int tid = threadIdx.x;
    if (blockIdx.x < PBLK) {
        // ---- partition: count w/ rank capture -> reserve -> dense scatter ----
        __shared__ int cnt[NBKT];
        __shared__ int base[NBKT];
        if (tid < NBKT) cnt[tid] = 0;
        __syncthreads();
        const int e0 = blockIdx.x * EPB + tid * 8;
        uint m[8]; float wv[8]; int rk[8]; bool val[8];
        if (e0 + 8 <= nnz) {
            int4 da = *(const int4*)(dst + e0), db = *(const int4*)(dst + e0 + 4);
            int4 sa = *(const int4*)(src + e0), sb = *(const int4*)(src + e0 + 4);
            float4 wa = *(const float4*)(w + e0), wb = *(const float4*)(w + e0 + 4);
            m[0] = (uint)(sa.x & 0xFFFF) | ((uint)da.x << 16); wv[0] = wa.x;
            m[1] = (uint)(sa.y & 0xFFFF) | ((uint)da.y << 16); wv[1] = wa.y;
            m[2] = (uint)(sa.z & 0xFFFF) | ((uint)da.z << 16); wv[2] = wa.z;
            m[3] = (uint)(sa.w & 0xFFFF) | ((uint)da.w << 16); wv[3] = wa.w;
            m[4] = (uint)(sb.x & 0xFFFF) | ((uint)db.x << 16); wv[4] = wb.x;
            m[5] = (uint)(sb.y & 0xFFFF) | ((uint)db.y << 16); wv[5] = wb.y;
            m[6] = (uint)(sb.z & 0xFFFF) | ((uint)db.z << 16); wv[6] = wb.z;
            m[7] = (uint)(sb.w & 0xFFFF) | ((uint)db.w << 16); wv[7] = wb.w;
            #pragma unroll
            for (int j = 0; j < 8; ++j) val[j] = true;
        } else {
            #pragma unroll
            for (int j = 0; j < 8; ++j) {
                int e = e0 + j;
                val[j] = (e < nnz);
                m[j]  = val[j] ? ((uint)(src[e] & 0xFFFF) | ((uint)dst[e] << 16)) : 0u;
                wv[j] = val[j] ? w[e] : 0.f;
            }
        }
        #pragma unroll
        for (int j = 0; j < 8; ++j)
            if (val[j]) rk[j] = atomicAdd(&cnt[m[j] >> 23], 1);
        __syncthreads();
        if (tid < NBKT) base[tid] = atomicAdd(&gcnt[tid], cnt[tid]);
        __syncthreads();
        #pragma unroll
        for (int j = 0; j < 8; ++j) {
            if (val[j]) {
                uint q = m[j] >> 23;
                int pos = base[q] + rk[j];
                if (pos < CAP) {   // statistically unreachable overflow guard
                    rec[(size_t)q * CAP + pos] = make_uint2(m[j], __float_as_uint(wv[j]));
                }
            }
        }
    } else {
        // ---- transpose x[32][IN] -> xt_bf16[IN][32], 32x128 slab ----
        __shared__ float tile[32][132];
        const int i0 = (blockIdx.x - PBLK) * 128;
        {
            int ty = tid >> 5, tx = tid & 31;          // row, col-group
            float4 vv = *(const float4*)(x + (size_t)ty * IN_SIZE + i0 + tx * 4);
            *(float4*)&tile[ty][tx * 4] = vv;
        }
        __syncthreads();
        {
            int c = tid >> 3, sub = tid & 7;           // col 0..127, row-group 0..7
            ushort4 o;
            __hip_bfloat16 h0 = __float2bfloat16(tile[sub * 4 + 0][c]);
            __hip_bfloat16 h1 = __float2bfloat16(tile[sub * 4 + 1][c]);
            __hip_bfloat16 h2 = __float2bfloat16(tile[sub * 4 + 2][c]);
            __hip_bfloat16 h3 = __float2bfloat16(tile[sub * 4 + 3][c]);
            o.x = *(ushort*)&h0; o.y = *(ushort*)&h1;
            o.z = *(ushort*)&h2; o.w = *(ushort*)&h3;
            *(ushort4*)(xt + ((size_t)(i0 + c)) * BATCH + sub * 4) = o;
        }
    }
}

// ---------------- per-bucket: rank-sort (8-padded) + wave-uniform accumulate ----------------
__global__ __launch_bounds__(1024) void accum_wave(
        const ushort* __restrict__ xt,
        const uint2*  __restrict__ rec,
        const int*    __restrict__ gcnt,
        float* __restrict__ out) {
    __shared__ uint2 bufB[PADCAP];   // sorted+padded records; reused as out-stage
    __shared__ int   soff[129];      // padded CSR offsets
    __shared__ int   scnt[128];      // counts (rank source)
    __shared__ int   sS[128];        // scan workspace

    const int q   = blockIdx.x;
    const int tid = threadIdx.x;
    const int n   = min(gcnt[q], CAP);
    const size_t beg = (size_t)q * CAP;

    if (tid < 128) scnt[tid] = 0;
    __syncthreads();

    // load records (<=3 per thread, static) + rank capture
    uint2 rr[3]; int rk[3]; bool v[3];
    #pragma unroll
    for (int u = 0; u < 3; ++u) {
        int j = tid + (u << 10);
        v[u] = (j < n);
        if (v[u]) {
            rr[u] = rec[beg + j];
            rk[u] = atomicAdd(&scnt[(rr[u].x >> 16) & 127u], 1);
        }
    }
    __syncthreads();

    // exclusive scan of PADDED counts (ceil(c/8)*8)
    int own = 0;
    if (tid < 128) { own = (scnt[tid] + 7) & ~7; sS[tid] = own; }
    __syncthreads();
    #pragma unroll
    for (int ofs = 1; ofs < 128; ofs <<= 1) {
        int t = 0;
        if (tid < 128 && tid >= ofs) t = sS[tid - ofs];
        __syncthreads();
        if (tid < 128) sS[tid] += t;
        __syncthreads();
    }
    if (tid < 128) {
        soff[tid] = sS[tid] - own;
        if (tid == 127) soff[128] = sS[127];
    }
    __syncthreads();

    // zero padded region, then scatter real records (pads stay w=0)
    const int pn = soff[128];
    for (int j = tid; j < pn; j += 1024) bufB[j] = make_uint2(0u, 0u);
    __syncthreads();
    #pragma unroll
    for (int u = 0; u < 3; ++u) {
        if (v[u]) {
            int d = (rr[u].x >> 16) & 127;
            bufB[soff[d] + rk[u]] = rr[u];
        }
    }
    __syncthreads();

    // wave-uniform accumulate: wave wv owns dsts wv*8..wv*8+7 sequentially.
    // Lane: eslot = (tid>>4)&3 (edge slot), k2 = (tid&15)*2 (batch pair).
    // Runs are multiples of 8 -> identical trips for all lanes of the wave.
    const int wv    = tid >> 6;          // wave 0..15
    const int eslot = (tid >> 4) & 3;
    const int k2    = (tid & 15) << 1;
    float2 a[8];
    #pragma unroll
    for (int dd = 0; dd < 8; ++dd) a[dd] = make_float2(0.f, 0.f);
    #pragma unroll
    for (int dd = 0; dd < 8; ++dd) {
        const int d = (wv << 3) + dd;
        int i = soff[d] + eslot;
        const int e2 = soff[d + 1];
        for (; i < e2; i += 8) {
            uint2 r0 = bufB[i];
            uint2 r1 = bufB[i + 4];
            uint p0 = *(const uint*)(xt + (r0.x & 0xFFFFu) * BATCH + k2);
            uint p1 = *(const uint*)(xt + (r1.x & 0xFFFFu) * BATCH + k2);
            float w0 = __uint_as_float(r0.y), w1 = __uint_as_float(r1.y);
            a[dd].x += w0 * bf2f((ushort)(p0 & 0xFFFFu));
            a[dd].y += w0 * bf2f((ushort)(p0 >> 16));
            a[dd].x += w1 * bf2f((ushort)(p1 & 0xFFFFu));
            a[dd].y += w1 * bf2f((ushort)(p1 >> 16));
        }
    }
    // combine the 4 edge-slots (lanes differing in bits 4,5)
    #pragma unroll
    for (int dd = 0; dd < 8; ++dd) {
        a[dd].x += __shfl_xor(a[dd].x, 16);
        a[dd].x += __shfl_xor(a[dd].x, 32);
        a[dd].y += __shfl_xor(a[dd].y, 16);
        a[dd].y += __shfl_xor(a[dd].y, 32);
    }
    __syncthreads();   // bufB dead
    // stage (reuse bufB as float stg[128][34]) + coalesced slab write
    float* stg = (float*)bufB;
    if (eslot == 0) {
        #pragma unroll
        for (int dd = 0; dd < 8; ++dd)
            *(float2*)&stg[((wv << 3) + dd) * 34 + k2] = a[dd];
    }
    __syncthreads();
    #pragma unroll
    for (int kk = 0; kk < 4; ++kk) {
        int idx = tid + (kk << 10);
        int row = idx >> 7;    // 0..31
        int col = idx & 127;
        out[(size_t)row * OUT_SIZE + (q << 7) + col] = stg[col * 34 + row];
    }
}

// ---------------- fallback ----------------
__global__ void zero_f4(float4* __restrict__ p, int n4) {
    int i = blockIdx.x * blockDim.x + threadIdx.x;
    if (i < n4) p[i] = make_float4(0.f, 0.f, 0.f, 0.f);
}
__global__ void scatter_direct(const float* __restrict__ x,
                               const float* __restrict__ w,
                               const int*   __restrict__ dst,
                               const int*   __restrict__ src,
                               float*       __restrict__ out,
                               int nnz) {
    int t = blockIdx.x * blockDim.x + threadIdx.x;
    int e = t >> 5;
    int b = t & 31;
    if (e < nnz) {
        atomicAdd(&out[(size_t)b * OUT_SIZE + dst[e]],
                  w[e] * x[(size_t)b * IN_SIZE + src[e]]);
    }
}

extern "C" void kernel_launch(void* const* d_in, const int* in_sizes, int n_in,
                              void* d_out, int out_size, void* d_ws, size_t ws_size,
                              hipStream_t stream) {
    const float* x   = (const float*)d_in[0];   // [32][65536]
    const float* w   = (const float*)d_in[1];   // [NNZ]
    const int*   dst = (const int*)d_in[2];     // [NNZ]
    const int*   src = (const int*)d_in[3];     // [NNZ]
    float*       out = (float*)d_out;           // [32][65536]
    const int nnz = in_sizes[1];

    // workspace layout (14 MiB + 2KB)
    const size_t XT_OFF   = 0;                                   // bf16 xt: 4 MiB
    const size_t REC_OFF  = (size_t)4 << 20;                     // uint2: 10 MiB
    const size_t GCNT_OFF = REC_OFF + (size_t)NBKT * CAP * 8;    // 2 KB
    const size_t WS_NEEDED = GCNT_OFF + NBKT * 4;

    if (ws_size >= WS_NEEDED && nnz <= (1 << 20)) {
        ushort* xt   = (ushort*)((char*)d_ws + XT_OFF);
        uint2*  rec  = (uint2*) ((char*)d_ws + REC_OFF);
        int*    gcnt = (int*)   ((char*)d_ws + GCNT_OFF);

        hipMemsetAsync(gcnt, 0, NBKT * sizeof(int), stream);
        prep_fused<<<PBLK + TBLK, 1024, 0, stream>>>(x, xt, dst, src, w,
                                                     gcnt, rec, nnz);
        accum_wave<<<NBKT, 1024, 0, stream>>>(xt, rec, gcnt, out);
    } else {
        int n4 = out_size / 4;
        zero_f4<<<(n4 + 255) / 256, 256, 0, stream>>>((float4*)d_out, n4);
        long long total = (long long)nnz * 32;
        int blocks = (int)((total + 255) / 256);
        scatter_direct<<<blocks, 256, 0, stream>>>(x, w, dst, src, out, nnz);
    }
}